// Round 1
// 207.000 us; speedup vs baseline: 1.5429x; 1.5429x over previous
//
#include <hip/hip_runtime.h>

#define N_NODES 100000
#define N_EDGES 1600000
#define IN_F 128
#define OUT_F 64

#define BROWS 32               // rows per bucket (100000 = 32 * 3125)
#define NBUCKET 3125
#define CAP 1024               // max edges a gather block sorts (mean 512, std 22.6)
#define BK_PAD 136             // padded k-stride (shorts) for b_lds: breaks 16-way bank repeat

#define NCHUNK 256             // edge chunks for the deterministic counting sort
#define EPC (N_EDGES / NCHUNK) // 6250 edges per chunk

typedef __attribute__((ext_vector_type(8))) short bf16x8;
typedef __attribute__((ext_vector_type(4))) float f32x4;

__device__ __forceinline__ unsigned short f32_to_bf16(float f) {
    const unsigned int b = __float_as_uint(f);
    return (unsigned short)((b + 0x7FFFu + ((b >> 16) & 1u)) >> 16);   // RNE
}
__device__ __forceinline__ float bf16_to_f32(unsigned short u) {
    return __uint_as_float(((unsigned int)u) << 16);
}

// ---------------- Kernel 1: support(bf16) = X @ W via MFMA 16x16x32 bf16 ----------------
// Block = 256 thr = 4 waves; wave handles 16 rows x 64 cols. W transposed in LDS
// as [n][k] bf16 (pad 136) so b-frags are ds_read_b128. A-frags read straight from
// global x (each element once, 32B/lane chunks). Frag layouts (m89/m91-verified):
// A: m=lane&15, k=quad*8+j.  B: n=lane&15, k=quad*8+j.  C/D: col=lane&15, row=quad*4+r.
__global__ __launch_bounds__(256) void gemm_kernel(
    const float* __restrict__ x, const float* __restrict__ w,
    unsigned short* __restrict__ support) {
    __shared__ unsigned short b_lds[OUT_F * BK_PAD];   // 17.4 KB

    const int t = threadIdx.x;
    // stage W transposed: w[k][n] (fp32, coalesced float4) -> b_lds[n*BK_PAD + k] (bf16)
    #pragma unroll
    for (int i = 0; i < 8; ++i) {
        const int f = t + 256 * i;            // float4 index; k = f>>4, n4 = (f&15)*4
        const int k = f >> 4, n4 = (f & 15) * 4;
        const float4 wv = ((const float4*)w)[f];
        b_lds[(n4 + 0) * BK_PAD + k] = f32_to_bf16(wv.x);
        b_lds[(n4 + 1) * BK_PAD + k] = f32_to_bf16(wv.y);
        b_lds[(n4 + 2) * BK_PAD + k] = f32_to_bf16(wv.z);
        b_lds[(n4 + 3) * BK_PAD + k] = f32_to_bf16(wv.w);
    }
    __syncthreads();

    const int lane = t & 63, wid = t >> 6;
    const int m16 = lane & 15, quad = lane >> 4;
    const int row0 = blockIdx.x * 64 + wid * 16;
    const int arow = min(row0 + m16, N_NODES - 1);
    const float* xr = x + (size_t)arow * IN_F;

    f32x4 acc[4];
    #pragma unroll
    for (int nt = 0; nt < 4; ++nt) acc[nt] = (f32x4){0.f, 0.f, 0.f, 0.f};

    #pragma unroll
    for (int kt = 0; kt < 4; ++kt) {
        const int kb = kt * 32 + quad * 8;
        const float4 a0 = *(const float4*)(xr + kb);
        const float4 a1 = *(const float4*)(xr + kb + 4);
        bf16x8 af;
        af[0] = (short)f32_to_bf16(a0.x); af[1] = (short)f32_to_bf16(a0.y);
        af[2] = (short)f32_to_bf16(a0.z); af[3] = (short)f32_to_bf16(a0.w);
        af[4] = (short)f32_to_bf16(a1.x); af[5] = (short)f32_to_bf16(a1.y);
        af[6] = (short)f32_to_bf16(a1.z); af[7] = (short)f32_to_bf16(a1.w);
        #pragma unroll
        for (int nt = 0; nt < 4; ++nt) {
            const bf16x8 bf = *(const bf16x8*)&b_lds[(nt * 16 + m16) * BK_PAD + kb];
            acc[nt] = __builtin_amdgcn_mfma_f32_16x16x32_bf16(af, bf, acc[nt], 0, 0, 0);
        }
    }

    #pragma unroll
    for (int nt = 0; nt < 4; ++nt) {
        #pragma unroll
        for (int r = 0; r < 4; ++r) {
            const int row = row0 + quad * 4 + r;
            if (row < N_NODES)
                support[(size_t)row * OUT_F + nt * 16 + m16] = f32_to_bf16(acc[nt][r]);
        }
    }
}

// ---------------- Kernel 2: per-chunk bucket histogram -> hist[chunk][bucket] ----------------
// No global atomics: LDS histogram, then coalesced store of the whole row.
__global__ __launch_bounds__(256) void count_kernel(const int* __restrict__ erow,
                                                    int* __restrict__ hist) {
    __shared__ int h[NBUCKET];   // 12.5 KB
    for (int i = threadIdx.x; i < NBUCKET; i += 256) h[i] = 0;
    __syncthreads();
    const int e0 = blockIdx.x * EPC;
    for (int i = threadIdx.x; i < EPC; i += 256)
        atomicAdd(&h[erow[e0 + i] >> 5], 1);
    __syncthreads();
    int* hrow = hist + (size_t)blockIdx.x * NBUCKET;
    for (int i = threadIdx.x; i < NBUCKET; i += 256) hrow[i] = h[i];
}

// ---------------- Kernel 3: per-bucket exclusive prefix over chunks (in-place) ----------------
// Thread owns one bucket column; 16-deep unroll keeps 16 loads in flight to hide
// the serial load->store recurrence. Emits bucket totals into gcount.
__global__ __launch_bounds__(256) void offs_kernel(int* __restrict__ hist,
                                                   int* __restrict__ gcount) {
    const int b = blockIdx.x * 256 + threadIdx.x;
    if (b >= NBUCKET) return;
    int run = 0;
    #pragma unroll 1
    for (int g = 0; g < NCHUNK / 16; ++g) {
        int h[16];
        #pragma unroll
        for (int u = 0; u < 16; ++u) h[u] = hist[(size_t)(g * 16 + u) * NBUCKET + b];
        #pragma unroll
        for (int u = 0; u < 16; ++u) {
            hist[(size_t)(g * 16 + u) * NBUCKET + b] = run;   // exclusive prefix, in-place
            run += h[u];
        }
    }
    gcount[b] = run;   // bucket total
}

// ---------------- Kernel 4: exclusive scan of bucket totals -> base ----------------
#define BPL ((NBUCKET + 63) / 64)   // 49 per lane
__global__ void base_kernel(const int* __restrict__ gcount, int* __restrict__ base) {
    const int lane = threadIdx.x;
    int v[BPL]; int s = 0;
    #pragma unroll
    for (int j = 0; j < BPL; ++j) { const int i = lane * BPL + j; v[j] = (i < NBUCKET) ? gcount[i] : 0; s += v[j]; }
    int incl = s;
    #pragma unroll
    for (int d = 1; d < 64; d <<= 1) { int tv = __shfl_up(incl, d); if (lane >= d) incl += tv; }
    int run = incl - s;
    #pragma unroll
    for (int j = 0; j < BPL; ++j) {
        const int i = lane * BPL + j;
        if (i < NBUCKET) { base[i] = run; run += v[j]; }
    }
    if (lane == 63) base[NBUCKET] = incl;
}

// ---------------- Kernel 5: deterministic reorder (LDS cursors, no global atomics) ----------------
// Block bid handles chunk (bid&7)*32 + bid>>3: consecutive chunks land on the SAME
// XCD (bid%8 round-robin), so the ~4 chunks that fill one 64B sedge line share an
// L2 -> partial 8B writes merge into full-line evictions (kills the 7x write amp).
// Slot = base[b] + prefix(hist[<chunk][b]) + LDS-atomic rank within chunk.
__global__ __launch_bounds__(256) void reorder_kernel(
    const int* __restrict__ erow, const int* __restrict__ ecol,
    const float* __restrict__ evals, const int* __restrict__ hist,
    const int* __restrict__ base, uint2* __restrict__ sedge) {
    __shared__ int lcur[NBUCKET];   // 12.5 KB
    const int t = threadIdx.x;
    const int chunk = ((blockIdx.x & 7) << 5) | (blockIdx.x >> 3);
    const int* csl = hist + (size_t)chunk * NBUCKET;
    for (int i = t; i < NBUCKET; i += 256) lcur[i] = csl[i] + base[i];
    __syncthreads();

    const int e0 = chunk * EPC;
    #pragma unroll 1
    for (int j = 0; j < 6; ++j) {          // 6 * 1024 = 6144 edges, 4-deep pipelined
        int idx[4]; int row[4];
        #pragma unroll
        for (int u = 0; u < 4; ++u) { idx[u] = j * 1024 + u * 256 + t; row[u] = erow[e0 + idx[u]]; }
        int p[4];
        #pragma unroll
        for (int u = 0; u < 4; ++u) p[u] = atomicAdd(&lcur[row[u] >> 5], 1);
        #pragma unroll
        for (int u = 0; u < 4; ++u) {
            uint2 ed;
            ed.x = (unsigned int)ecol[e0 + idx[u]] | (((unsigned int)row[u] & 31u) << 20);
            ed.y = __float_as_uint(evals[e0 + idx[u]]);
            sedge[p[u]] = ed;
        }
    }
    const int i = 6144 + t;                // tail: 6250 - 6144 = 106 edges
    if (i < EPC) {
        const int row = erow[e0 + i];
        const int p = atomicAdd(&lcur[row >> 5], 1);
        uint2 ed;
        ed.x = (unsigned int)ecol[e0 + i] | (((unsigned int)row & 31u) << 20);
        ed.y = __float_as_uint(evals[e0 + i]);
        sedge[p] = ed;
    }
}

// ---------------- Kernel 6: counting-sort by row + register accumulation ----------------
__global__ __launch_bounds__(256) void gather_kernel(
    const unsigned short* __restrict__ support, const uint2* __restrict__ sedge,
    const int* __restrict__ base, const float* __restrict__ bias,
    float* __restrict__ out) {
    __shared__ uint2 sdata[CAP];    // 8 KB sorted payloads
    __shared__ int bcnt[BROWS];
    __shared__ int bptr[BROWS + 1];
    __shared__ int boff[BROWS];

    const int t = threadIdx.x;
    const int k = blockIdx.x;
    const int start = base[k], end = base[k + 1];
    const int n = min(end - start, CAP);

    if (t < BROWS) bcnt[t] = 0;
    __syncthreads();

    uint2 my[4]; int mb[4];
    #pragma unroll
    for (int j = 0; j < 4; ++j) {
        const int i = t + j * 256;
        mb[j] = -1;
        if (i < n) {
            my[j] = sedge[start + i];
            mb[j] = (my[j].x >> 20) & 31;
            atomicAdd(&bcnt[mb[j]], 1);
        }
    }
    __syncthreads();

    if (t < 64) {
        const int lane = t;
        const int v = (lane < BROWS) ? bcnt[lane] : 0;
        int incl = v;
        #pragma unroll
        for (int d = 1; d < 32; d <<= 1) { int tv = __shfl_up(incl, d); if (lane >= d) incl += tv; }
        if (lane < BROWS) { bptr[lane] = incl - v; boff[lane] = incl - v; }
        if (lane == BROWS - 1) bptr[BROWS] = incl;
    }
    __syncthreads();

    #pragma unroll
    for (int j = 0; j < 4; ++j) {
        if (mb[j] >= 0) {
            const int p = atomicAdd(&boff[mb[j]], 1);
            sdata[p] = my[j];
        }
    }
    __syncthreads();

    const int wid = t >> 6, lane = t & 63;
    const float bb = bias[lane];
    for (int r8 = 0; r8 < 8; ++r8) {
        const int r = wid * 8 + r8;
        const int s0 = bptr[r], s1 = bptr[r + 1];
        float acc = 0.f;
        int j = s0;
        for (; j + 8 <= s1; j += 8) {
            uint2 ed[8];
            #pragma unroll
            for (int u = 0; u < 8; ++u) ed[u] = sdata[j + u];
            float g[8];
            #pragma unroll
            for (int u = 0; u < 8; ++u)
                g[u] = bf16_to_f32(support[(size_t)(ed[u].x & 0xFFFFFu) * OUT_F + lane]);
            #pragma unroll
            for (int u = 0; u < 8; ++u)
                acc += g[u] * __uint_as_float(ed[u].y);
        }
        for (; j < s1; ++j) {
            const uint2 ed = sdata[j];
            acc += bf16_to_f32(support[(size_t)(ed.x & 0xFFFFFu) * OUT_F + lane])
                   * __uint_as_float(ed.y);
        }
        out[(size_t)(k * BROWS + r) * OUT_F + lane] = acc + bb;
    }

    if (end - start > CAP) {   // overflow insurance (statistically never)
        __syncthreads();
        for (int i = CAP + wid; i < end - start; i += 4) {
            const uint2 ed = sedge[start + i];
            const float g = bf16_to_f32(support[(size_t)(ed.x & 0xFFFFFu) * OUT_F + lane]);
            atomicAdd(&out[(size_t)(k * BROWS + ((ed.x >> 20) & 31)) * OUT_F + lane],
                      g * __uint_as_float(ed.y));
        }
    }
}

// ---------------- Fallback (ws too small): bias-init + atomic scatter ----------------
__global__ __launch_bounds__(256) void init_out_kernel(const float* __restrict__ bias,
                                                       float* __restrict__ out) {
    const size_t i = (size_t)blockIdx.x * 256 + threadIdx.x;
    if (i < (size_t)N_NODES * OUT_F) out[i] = bias[i & 63];
}
__global__ __launch_bounds__(256) void scatter_atomic_kernel(
    const unsigned short* __restrict__ support, const int* __restrict__ erow,
    const int* __restrict__ ecol, const float* __restrict__ evals,
    float* __restrict__ out) {
    const int wid = (blockIdx.x * 256 + threadIdx.x) >> 6;
    const int nw = gridDim.x * 4;
    const int lane = threadIdx.x & 63;
    const int n_iters = N_EDGES / 8;
    for (int it0 = wid; it0 < n_iters; it0 += nw) {
        const int e0 = __builtin_amdgcn_readfirstlane(it0) * 8;
        int src[8], dst[8]; float val[8];
        #pragma unroll
        for (int u = 0; u < 8; ++u) { src[u] = ecol[e0 + u]; dst[u] = erow[e0 + u]; val[u] = evals[e0 + u]; }
        float g[8];
        #pragma unroll
        for (int u = 0; u < 8; ++u) g[u] = bf16_to_f32(support[(size_t)src[u] * OUT_F + lane]);
        #pragma unroll
        for (int u = 0; u < 8; ++u) atomicAdd(&out[(size_t)dst[u] * OUT_F + lane], g[u] * val[u]);
    }
}

extern "C" void kernel_launch(void* const* d_in, const int* in_sizes, int n_in,
                              void* d_out, int out_size, void* d_ws, size_t ws_size,
                              hipStream_t stream) {
    const float* x     = (const float*)d_in[0];
    const float* w     = (const float*)d_in[1];
    const float* bias  = (const float*)d_in[2];
    const int* erow    = (const int*)d_in[3];
    const int* ecol    = (const int*)d_in[4];
    const float* evals = (const float*)d_in[5];
    float* out = (float*)d_out;

    char* p = (char*)d_ws;
    unsigned short* support = (unsigned short*)p;     size_t o = (size_t)N_NODES * OUT_F * 2;  // 12.8 MB
    int* gcount = (int*)(p + o);                      o += (size_t)(NBUCKET + 3) / 4 * 16;
    int* base   = (int*)(p + o);                      o += (size_t)(NBUCKET + 1 + 3) / 4 * 16;
    int* hist   = (int*)(p + o);                      o += (size_t)NCHUNK * NBUCKET * 4;       // 3.2 MB
    uint2* sedge = (uint2*)(p + o);                   o += (size_t)N_EDGES * 8;                // 12.8 MB

    gemm_kernel<<<(N_NODES + 63) / 64, 256, 0, stream>>>(x, w, support);

    if (ws_size >= o) {
        count_kernel<<<NCHUNK, 256, 0, stream>>>(erow, hist);
        offs_kernel<<<(NBUCKET + 255) / 256, 256, 0, stream>>>(hist, gcount);
        base_kernel<<<1, 64, 0, stream>>>(gcount, base);
        reorder_kernel<<<NCHUNK, 256, 0, stream>>>(erow, ecol, evals, hist, base, sedge);
        gather_kernel<<<NBUCKET, 256, 0, stream>>>(support, sedge, base, bias, out);
    } else {
        init_out_kernel<<<((N_NODES * OUT_F) + 255) / 256, 256, 0, stream>>>(bias, out);
        scatter_atomic_kernel<<<2048, 256, 0, stream>>>(support, erow, ecol, evals, out);
    }
}

// Round 2
// 183.159 us; speedup vs baseline: 1.7437x; 1.1302x over previous
//
#include <hip/hip_runtime.h>

#define N_NODES 100000
#define N_EDGES 1600000
#define IN_F 128
#define OUT_F 64

#define BROWS 32               // rows per bucket (100000 = 32 * 3125)
#define NBUCKET 3125
#define CAP 1024               // max edges a gather block sorts (mean 512, std 22.6)
#define BK_PAD 136             // padded k-stride (shorts) for b_lds: breaks 16-way bank repeat

#define NCHUNK 256             // edge chunks for the deterministic counting sort
#define EPC (N_EDGES / NCHUNK) // 6250 edges per chunk

typedef __attribute__((ext_vector_type(8))) short bf16x8;
typedef __attribute__((ext_vector_type(4))) float f32x4;

__device__ __forceinline__ unsigned short f32_to_bf16(float f) {
    const unsigned int b = __float_as_uint(f);
    return (unsigned short)((b + 0x7FFFu + ((b >> 16) & 1u)) >> 16);   // RNE
}
__device__ __forceinline__ float bf16_to_f32(unsigned short u) {
    return __uint_as_float(((unsigned int)u) << 16);
}
// unpack low/high bf16 of a uint32 (1 VALU each)
__device__ __forceinline__ float bflo(unsigned int u) { return __uint_as_float(u << 16); }
__device__ __forceinline__ float bfhi(unsigned int u) { return __uint_as_float(u & 0xFFFF0000u); }

// ---------------- Kernel 1: support(bf16) = X @ W via MFMA 16x16x32 bf16 ----------------
// Block = 256 thr = 4 waves; wave handles 16 rows x 64 cols. W transposed in LDS
// as [n][k] bf16 (pad 136) so b-frags are ds_read_b128. A-frags read straight from
// global x (each element once, 32B/lane chunks). Frag layouts (m89/m91-verified):
// A: m=lane&15, k=quad*8+j.  B: n=lane&15, k=quad*8+j.  C/D: col=lane&15, row=quad*4+r.
__global__ __launch_bounds__(256) void gemm_kernel(
    const float* __restrict__ x, const float* __restrict__ w,
    unsigned short* __restrict__ support) {
    __shared__ unsigned short b_lds[OUT_F * BK_PAD];   // 17.4 KB

    const int t = threadIdx.x;
    // stage W transposed: w[k][n] (fp32, coalesced float4) -> b_lds[n*BK_PAD + k] (bf16)
    #pragma unroll
    for (int i = 0; i < 8; ++i) {
        const int f = t + 256 * i;            // float4 index; k = f>>4, n4 = (f&15)*4
        const int k = f >> 4, n4 = (f & 15) * 4;
        const float4 wv = ((const float4*)w)[f];
        b_lds[(n4 + 0) * BK_PAD + k] = f32_to_bf16(wv.x);
        b_lds[(n4 + 1) * BK_PAD + k] = f32_to_bf16(wv.y);
        b_lds[(n4 + 2) * BK_PAD + k] = f32_to_bf16(wv.z);
        b_lds[(n4 + 3) * BK_PAD + k] = f32_to_bf16(wv.w);
    }
    __syncthreads();

    const int lane = t & 63, wid = t >> 6;
    const int m16 = lane & 15, quad = lane >> 4;
    const int row0 = blockIdx.x * 64 + wid * 16;
    const int arow = min(row0 + m16, N_NODES - 1);
    const float* xr = x + (size_t)arow * IN_F;

    f32x4 acc[4];
    #pragma unroll
    for (int nt = 0; nt < 4; ++nt) acc[nt] = (f32x4){0.f, 0.f, 0.f, 0.f};

    #pragma unroll
    for (int kt = 0; kt < 4; ++kt) {
        const int kb = kt * 32 + quad * 8;
        const float4 a0 = *(const float4*)(xr + kb);
        const float4 a1 = *(const float4*)(xr + kb + 4);
        bf16x8 af;
        af[0] = (short)f32_to_bf16(a0.x); af[1] = (short)f32_to_bf16(a0.y);
        af[2] = (short)f32_to_bf16(a0.z); af[3] = (short)f32_to_bf16(a0.w);
        af[4] = (short)f32_to_bf16(a1.x); af[5] = (short)f32_to_bf16(a1.y);
        af[6] = (short)f32_to_bf16(a1.z); af[7] = (short)f32_to_bf16(a1.w);
        #pragma unroll
        for (int nt = 0; nt < 4; ++nt) {
            const bf16x8 bf = *(const bf16x8*)&b_lds[(nt * 16 + m16) * BK_PAD + kb];
            acc[nt] = __builtin_amdgcn_mfma_f32_16x16x32_bf16(af, bf, acc[nt], 0, 0, 0);
        }
    }

    #pragma unroll
    for (int nt = 0; nt < 4; ++nt) {
        #pragma unroll
        for (int r = 0; r < 4; ++r) {
            const int row = row0 + quad * 4 + r;
            if (row < N_NODES)
                support[(size_t)row * OUT_F + nt * 16 + m16] = f32_to_bf16(acc[nt][r]);
        }
    }
}

// ---------------- Kernel 2: per-chunk bucket histogram -> hist[chunk][bucket] ----------------
// 1024-thread blocks: 16 waves/CU (was 4 -> 12.5% occupancy, latency-exposed).
// No global atomics: LDS histogram, then coalesced store of the whole row.
__global__ __launch_bounds__(1024) void count_kernel(const int* __restrict__ erow,
                                                     int* __restrict__ hist) {
    __shared__ int h[NBUCKET];   // 12.5 KB
    const int t = threadIdx.x;
    for (int i = t; i < NBUCKET; i += 1024) h[i] = 0;
    __syncthreads();
    const int e0 = blockIdx.x * EPC;
    #pragma unroll 1
    for (int j = 0; j < 6144; j += 2048) {       // 6144 = 6 * 1024, 2-deep batched
        const int r0 = erow[e0 + j + t];
        const int r1 = erow[e0 + j + 1024 + t];
        atomicAdd(&h[r0 >> 5], 1);
        atomicAdd(&h[r1 >> 5], 1);
    }
    if (6144 + t < EPC)                          // tail: 106 edges
        atomicAdd(&h[erow[e0 + 6144 + t] >> 5], 1);
    __syncthreads();
    int* hrow = hist + (size_t)blockIdx.x * NBUCKET;
    for (int i = t; i < NBUCKET; i += 1024) hrow[i] = h[i];
}

// ---------------- Kernel 3: per-bucket exclusive prefix over chunks (in-place) ----------------
// Thread owns one bucket column; 16-deep unroll keeps 16 loads in flight to hide
// the serial load->store recurrence. Emits bucket totals into gcount.
__global__ __launch_bounds__(256) void offs_kernel(int* __restrict__ hist,
                                                   int* __restrict__ gcount) {
    const int b = blockIdx.x * 256 + threadIdx.x;
    if (b >= NBUCKET) return;
    int run = 0;
    #pragma unroll 1
    for (int g = 0; g < NCHUNK / 16; ++g) {
        int h[16];
        #pragma unroll
        for (int u = 0; u < 16; ++u) h[u] = hist[(size_t)(g * 16 + u) * NBUCKET + b];
        #pragma unroll
        for (int u = 0; u < 16; ++u) {
            hist[(size_t)(g * 16 + u) * NBUCKET + b] = run;   // exclusive prefix, in-place
            run += h[u];
        }
    }
    gcount[b] = run;   // bucket total
}

// ---------------- Kernel 4: exclusive scan of bucket totals -> base ----------------
#define BPL ((NBUCKET + 63) / 64)   // 49 per lane
__global__ void base_kernel(const int* __restrict__ gcount, int* __restrict__ base) {
    const int lane = threadIdx.x;
    int v[BPL]; int s = 0;
    #pragma unroll
    for (int j = 0; j < BPL; ++j) { const int i = lane * BPL + j; v[j] = (i < NBUCKET) ? gcount[i] : 0; s += v[j]; }
    int incl = s;
    #pragma unroll
    for (int d = 1; d < 64; d <<= 1) { int tv = __shfl_up(incl, d); if (lane >= d) incl += tv; }
    int run = incl - s;
    #pragma unroll
    for (int j = 0; j < BPL; ++j) {
        const int i = lane * BPL + j;
        if (i < NBUCKET) { base[i] = run; run += v[j]; }
    }
    if (lane == 63) base[NBUCKET] = incl;
}

// ---------------- Kernel 5: deterministic reorder (LDS cursors, no global atomics) ----------------
// 1024-thread blocks (16 waves/CU). Block bid handles chunk (bid&7)*32 + bid>>3:
// consecutive chunks land on the SAME XCD (bid%8 round-robin), so the ~4 chunks
// that fill one 64B sedge line share an L2 -> partial 8B writes merge into
// full-line evictions. Slot = base[b] + prefix(hist[<chunk][b]) + LDS-atomic rank.
__global__ __launch_bounds__(1024) void reorder_kernel(
    const int* __restrict__ erow, const int* __restrict__ ecol,
    const float* __restrict__ evals, const int* __restrict__ hist,
    const int* __restrict__ base, uint2* __restrict__ sedge) {
    __shared__ int lcur[NBUCKET];   // 12.5 KB
    const int t = threadIdx.x;
    const int chunk = ((blockIdx.x & 7) << 5) | (blockIdx.x >> 3);
    const int* csl = hist + (size_t)chunk * NBUCKET;
    for (int i = t; i < NBUCKET; i += 1024) lcur[i] = csl[i] + base[i];
    __syncthreads();

    const int e0 = chunk * EPC;
    #pragma unroll 1
    for (int j = 0; j < 6144; j += 2048) {       // 2-deep pipelined
        const int i0 = e0 + j + t, i1 = i0 + 1024;
        const int r0 = erow[i0], r1 = erow[i1];
        const int c0 = ecol[i0], c1 = ecol[i1];
        const float v0 = evals[i0], v1 = evals[i1];
        const int p0 = atomicAdd(&lcur[r0 >> 5], 1);
        const int p1 = atomicAdd(&lcur[r1 >> 5], 1);
        uint2 ed0, ed1;
        ed0.x = (unsigned int)c0 | (((unsigned int)r0 & 31u) << 20);
        ed0.y = __float_as_uint(v0);
        ed1.x = (unsigned int)c1 | (((unsigned int)r1 & 31u) << 20);
        ed1.y = __float_as_uint(v1);
        sedge[p0] = ed0;
        sedge[p1] = ed1;
    }
    const int i = 6144 + t;                      // tail: 106 edges
    if (i < EPC) {
        const int row = erow[e0 + i];
        const int p = atomicAdd(&lcur[row >> 5], 1);
        uint2 ed;
        ed.x = (unsigned int)ecol[e0 + i] | (((unsigned int)row & 31u) << 20);
        ed.y = __float_as_uint(evals[e0 + i]);
        sedge[p] = ed;
    }
}

// ---------------- Kernel 6: counting-sort by row + register accumulation ----------------
// Accumulation phase: 4 edge-groups x 16 lanes x 4 cols/lane (uint2 = 4 bf16 per
// load). 4x fewer gather-load instrs, ~2x fewer hot-loop VALU than 1 col/lane.
// Cross-group reduce (shfl_xor 16,32) once per row; g==0 lanes store float4.
__global__ __launch_bounds__(256) void gather_kernel(
    const unsigned short* __restrict__ support, const uint2* __restrict__ sedge,
    const int* __restrict__ base, const float* __restrict__ bias,
    float* __restrict__ out) {
    __shared__ uint2 sdata[CAP];    // 8 KB sorted payloads
    __shared__ int bcnt[BROWS];
    __shared__ int bptr[BROWS + 1];
    __shared__ int boff[BROWS];

    const int t = threadIdx.x;
    const int k = blockIdx.x;
    const int start = base[k], end = base[k + 1];
    const int n = min(end - start, CAP);

    if (t < BROWS) bcnt[t] = 0;
    __syncthreads();

    uint2 my[4]; int mb[4];
    #pragma unroll
    for (int j = 0; j < 4; ++j) {
        const int i = t + j * 256;
        mb[j] = -1;
        if (i < n) {
            my[j] = sedge[start + i];
            mb[j] = (my[j].x >> 20) & 31;
            atomicAdd(&bcnt[mb[j]], 1);
        }
    }
    __syncthreads();

    if (t < 64) {
        const int lane = t;
        const int v = (lane < BROWS) ? bcnt[lane] : 0;
        int incl = v;
        #pragma unroll
        for (int d = 1; d < 32; d <<= 1) { int tv = __shfl_up(incl, d); if (lane >= d) incl += tv; }
        if (lane < BROWS) { bptr[lane] = incl - v; boff[lane] = incl - v; }
        if (lane == BROWS - 1) bptr[BROWS] = incl;
    }
    __syncthreads();

    #pragma unroll
    for (int j = 0; j < 4; ++j) {
        if (mb[j] >= 0) {
            const int p = atomicAdd(&boff[mb[j]], 1);
            sdata[p] = my[j];
        }
    }
    __syncthreads();

    const int wid = t >> 6, lane = t & 63;
    const int eg = lane >> 4;          // edge-group 0..3
    const int c4 = lane & 15;          // col-quad: cols 4*c4 .. 4*c4+3
    const float4 bb = ((const float4*)bias)[c4];

    for (int r8 = 0; r8 < 8; ++r8) {
        const int r = wid * 8 + r8;
        const int s0 = bptr[r], s1 = bptr[r + 1];
        float a0 = 0.f, a1 = 0.f, a2 = 0.f, a3 = 0.f;
        int j = s0;
        for (; j + 8 <= s1; j += 8) {            // 2 quads in flight
            const uint2 e0 = sdata[j + eg];
            const uint2 e1 = sdata[j + 4 + eg];
            const uint2 g0 = *(const uint2*)(support + (size_t)(e0.x & 0xFFFFFu) * OUT_F + c4 * 4);
            const uint2 g1 = *(const uint2*)(support + (size_t)(e1.x & 0xFFFFFu) * OUT_F + c4 * 4);
            const float v0 = __uint_as_float(e0.y), v1 = __uint_as_float(e1.y);
            a0 += v0 * bflo(g0.x); a1 += v0 * bfhi(g0.x);
            a2 += v0 * bflo(g0.y); a3 += v0 * bfhi(g0.y);
            a0 += v1 * bflo(g1.x); a1 += v1 * bfhi(g1.x);
            a2 += v1 * bflo(g1.y); a3 += v1 * bfhi(g1.y);
        }
        for (; j < s1; j += 4) {                 // predicated quad tail (0..7 edges)
            const int jj = j + eg;
            const bool act = jj < s1;
            const uint2 ed = sdata[act ? jj : j];       // j < s1 here, safe
            const float v = act ? __uint_as_float(ed.y) : 0.f;
            const uint2 gv = *(const uint2*)(support + (size_t)(ed.x & 0xFFFFFu) * OUT_F + c4 * 4);
            a0 += v * bflo(gv.x); a1 += v * bfhi(gv.x);
            a2 += v * bflo(gv.y); a3 += v * bfhi(gv.y);
        }
        a0 += __shfl_xor(a0, 16); a0 += __shfl_xor(a0, 32);
        a1 += __shfl_xor(a1, 16); a1 += __shfl_xor(a1, 32);
        a2 += __shfl_xor(a2, 16); a2 += __shfl_xor(a2, 32);
        a3 += __shfl_xor(a3, 16); a3 += __shfl_xor(a3, 32);
        if (eg == 0) {
            float4 o;
            o.x = a0 + bb.x; o.y = a1 + bb.y; o.z = a2 + bb.z; o.w = a3 + bb.w;
            *(float4*)(out + (size_t)(k * BROWS + r) * OUT_F + c4 * 4) = o;
        }
    }

    if (end - start > CAP) {   // overflow insurance (statistically never)
        __syncthreads();
        for (int i = CAP + wid; i < end - start; i += 4) {
            const uint2 ed = sedge[start + i];
            const float g = bf16_to_f32(support[(size_t)(ed.x & 0xFFFFFu) * OUT_F + lane]);
            atomicAdd(&out[(size_t)(k * BROWS + ((ed.x >> 20) & 31)) * OUT_F + lane],
                      g * __uint_as_float(ed.y));
        }
    }
}

// ---------------- Fallback (ws too small): bias-init + atomic scatter ----------------
__global__ __launch_bounds__(256) void init_out_kernel(const float* __restrict__ bias,
                                                       float* __restrict__ out) {
    const size_t i = (size_t)blockIdx.x * 256 + threadIdx.x;
    if (i < (size_t)N_NODES * OUT_F) out[i] = bias[i & 63];
}
__global__ __launch_bounds__(256) void scatter_atomic_kernel(
    const unsigned short* __restrict__ support, const int* __restrict__ erow,
    const int* __restrict__ ecol, const float* __restrict__ evals,
    float* __restrict__ out) {
    const int wid = (blockIdx.x * 256 + threadIdx.x) >> 6;
    const int nw = gridDim.x * 4;
    const int lane = threadIdx.x & 63;
    const int n_iters = N_EDGES / 8;
    for (int it0 = wid; it0 < n_iters; it0 += nw) {
        const int e0 = __builtin_amdgcn_readfirstlane(it0) * 8;
        int src[8], dst[8]; float val[8];
        #pragma unroll
        for (int u = 0; u < 8; ++u) { src[u] = ecol[e0 + u]; dst[u] = erow[e0 + u]; val[u] = evals[e0 + u]; }
        float g[8];
        #pragma unroll
        for (int u = 0; u < 8; ++u) g[u] = bf16_to_f32(support[(size_t)src[u] * OUT_F + lane]);
        #pragma unroll
        for (int u = 0; u < 8; ++u) atomicAdd(&out[(size_t)dst[u] * OUT_F + lane], g[u] * val[u]);
    }
}

extern "C" void kernel_launch(void* const* d_in, const int* in_sizes, int n_in,
                              void* d_out, int out_size, void* d_ws, size_t ws_size,
                              hipStream_t stream) {
    const float* x     = (const float*)d_in[0];
    const float* w     = (const float*)d_in[1];
    const float* bias  = (const float*)d_in[2];
    const int* erow    = (const int*)d_in[3];
    const int* ecol    = (const int*)d_in[4];
    const float* evals = (const float*)d_in[5];
    float* out = (float*)d_out;

    char* p = (char*)d_ws;
    unsigned short* support = (unsigned short*)p;     size_t o = (size_t)N_NODES * OUT_F * 2;  // 12.8 MB
    int* gcount = (int*)(p + o);                      o += (size_t)(NBUCKET + 3) / 4 * 16;
    int* base   = (int*)(p + o);                      o += (size_t)(NBUCKET + 1 + 3) / 4 * 16;
    int* hist   = (int*)(p + o);                      o += (size_t)NCHUNK * NBUCKET * 4;       // 3.2 MB
    uint2* sedge = (uint2*)(p + o);                   o += (size_t)N_EDGES * 8;                // 12.8 MB

    gemm_kernel<<<(N_NODES + 63) / 64, 256, 0, stream>>>(x, w, support);

    if (ws_size >= o) {
        count_kernel<<<NCHUNK, 1024, 0, stream>>>(erow, hist);
        offs_kernel<<<(NBUCKET + 255) / 256, 256, 0, stream>>>(hist, gcount);
        base_kernel<<<1, 64, 0, stream>>>(gcount, base);
        reorder_kernel<<<NCHUNK, 1024, 0, stream>>>(erow, ecol, evals, hist, base, sedge);
        gather_kernel<<<NBUCKET, 256, 0, stream>>>(support, sedge, base, bias, out);
    } else {
        init_out_kernel<<<((N_NODES * OUT_F) + 255) / 256, 256, 0, stream>>>(bias, out);
        scatter_atomic_kernel<<<2048, 256, 0, stream>>>(support, erow, ecol, evals, out);
    }
}

// Round 3
// 171.400 us; speedup vs baseline: 1.8633x; 1.0686x over previous
//
#include <hip/hip_runtime.h>

#define N_NODES 100000
#define N_EDGES 1600000
#define IN_F 128
#define OUT_F 64

#define BROWS 32               // rows per bucket (100000 = 32 * 3125)
#define NBUCKET 3125
#define CAP 1024               // max edges a gather block handles (mean 512, std 22.6)
#define BK_PAD 136             // padded k-stride (shorts) for b_lds: breaks 16-way bank repeat

#define NCHUNK 256             // edge chunks; == gather blockDim so thread==chunk
#define EPC (N_EDGES / NCHUNK) // 6250 edges per chunk (exact)
#define NPOS (NBUCKET + 1)     // 3126: per-chunk prefix incl. sentinel

typedef __attribute__((ext_vector_type(8))) short bf16x8;
typedef __attribute__((ext_vector_type(4))) float f32x4;

__device__ __forceinline__ unsigned short f32_to_bf16(float f) {
    const unsigned int b = __float_as_uint(f);
    return (unsigned short)((b + 0x7FFFu + ((b >> 16) & 1u)) >> 16);   // RNE
}
__device__ __forceinline__ float bf16_to_f32(unsigned short u) {
    return __uint_as_float(((unsigned int)u) << 16);
}
// unpack low/high bf16 of a uint32 (1 VALU each)
__device__ __forceinline__ float bflo(unsigned int u) { return __uint_as_float(u << 16); }
__device__ __forceinline__ float bfhi(unsigned int u) { return __uint_as_float(u & 0xFFFF0000u); }

// ---------------- Kernel 1: support(bf16) = X @ W via MFMA 16x16x32 bf16 ----------------
// Block = 256 thr = 4 waves; wave handles 16 rows x 64 cols. W transposed in LDS
// as [n][k] bf16 (pad 136) so b-frags are ds_read_b128. A-frags read straight from
// global x (each element once, 32B/lane chunks). Frag layouts (m89/m91-verified):
// A: m=lane&15, k=quad*8+j.  B: n=lane&15, k=quad*8+j.  C/D: col=lane&15, row=quad*4+r.
__global__ __launch_bounds__(256) void gemm_kernel(
    const float* __restrict__ x, const float* __restrict__ w,
    unsigned short* __restrict__ support) {
    __shared__ unsigned short b_lds[OUT_F * BK_PAD];   // 17.4 KB

    const int t = threadIdx.x;
    #pragma unroll
    for (int i = 0; i < 8; ++i) {
        const int f = t + 256 * i;            // float4 index; k = f>>4, n4 = (f&15)*4
        const int k = f >> 4, n4 = (f & 15) * 4;
        const float4 wv = ((const float4*)w)[f];
        b_lds[(n4 + 0) * BK_PAD + k] = f32_to_bf16(wv.x);
        b_lds[(n4 + 1) * BK_PAD + k] = f32_to_bf16(wv.y);
        b_lds[(n4 + 2) * BK_PAD + k] = f32_to_bf16(wv.z);
        b_lds[(n4 + 3) * BK_PAD + k] = f32_to_bf16(wv.w);
    }
    __syncthreads();

    const int lane = t & 63, wid = t >> 6;
    const int m16 = lane & 15, quad = lane >> 4;
    const int row0 = blockIdx.x * 64 + wid * 16;
    const int arow = min(row0 + m16, N_NODES - 1);
    const float* xr = x + (size_t)arow * IN_F;

    f32x4 acc[4];
    #pragma unroll
    for (int nt = 0; nt < 4; ++nt) acc[nt] = (f32x4){0.f, 0.f, 0.f, 0.f};

    #pragma unroll
    for (int kt = 0; kt < 4; ++kt) {
        const int kb = kt * 32 + quad * 8;
        const float4 a0 = *(const float4*)(xr + kb);
        const float4 a1 = *(const float4*)(xr + kb + 4);
        bf16x8 af;
        af[0] = (short)f32_to_bf16(a0.x); af[1] = (short)f32_to_bf16(a0.y);
        af[2] = (short)f32_to_bf16(a0.z); af[3] = (short)f32_to_bf16(a0.w);
        af[4] = (short)f32_to_bf16(a1.x); af[5] = (short)f32_to_bf16(a1.y);
        af[6] = (short)f32_to_bf16(a1.z); af[7] = (short)f32_to_bf16(a1.w);
        #pragma unroll
        for (int nt = 0; nt < 4; ++nt) {
            const bf16x8 bf = *(const bf16x8*)&b_lds[(nt * 16 + m16) * BK_PAD + kb];
            acc[nt] = __builtin_amdgcn_mfma_f32_16x16x32_bf16(af, bf, acc[nt], 0, 0, 0);
        }
    }

    #pragma unroll
    for (int nt = 0; nt < 4; ++nt) {
        #pragma unroll
        for (int r = 0; r < 4; ++r) {
            const int row = row0 + quad * 4 + r;
            if (row < N_NODES)
                support[(size_t)row * OUT_F + nt * 16 + m16] = f32_to_bf16(acc[nt][r]);
        }
    }
}

// ---------------- Kernel 2: chunk-local bucket sort (fuses count+offs+base+reorder) ----------
// Block = chunk = 6250 edges. LDS histogram -> block scan -> persist per-chunk prefix
// pos[c][*] (coalesced) -> LDS-rank scatter into sd[] -> write sd chunk-contiguous
// (perfectly coalesced; no scattered global stores anywhere in the pipeline now).
__global__ __launch_bounds__(1024) void sort_kernel(
    const int* __restrict__ erow, const int* __restrict__ ecol,
    const float* __restrict__ evals, int* __restrict__ pos_g,
    uint2* __restrict__ sedge) {
    __shared__ uint2 sd[EPC];        // 50 KB bucket-sorted payloads
    __shared__ int pos[NPOS];        // 12.5 KB histogram -> prefix -> cursors
    __shared__ int wofs[16];

    const int t = threadIdx.x;
    const int c = blockIdx.x;
    const int e0 = c * EPC;

    for (int i = t; i < NPOS; i += 1024) pos[i] = 0;
    __syncthreads();

    // pass 1: histogram (erow re-read in pass 2 is L2-hot: 25 KB slice/block)
    #pragma unroll 1
    for (int j = t; j < EPC; j += 1024)
        atomicAdd(&pos[erow[e0 + j] >> 5], 1);
    __syncthreads();

    // block-exclusive scan over 3125 buckets, 4 per thread
    int v[4]; int s = 0;
    #pragma unroll
    for (int j = 0; j < 4; ++j) {
        const int i = t * 4 + j;
        v[j] = (i < NBUCKET) ? pos[i] : 0;
        s += v[j];
    }
    const int lane = t & 63, wid = t >> 6;
    int incl = s;
    #pragma unroll
    for (int d = 1; d < 64; d <<= 1) { int tv = __shfl_up(incl, d); if (lane >= d) incl += tv; }
    if (lane == 63) wofs[wid] = incl;
    __syncthreads();
    int wbase = 0;
    #pragma unroll
    for (int wj = 0; wj < 16; ++wj) wbase += (wj < wid) ? wofs[wj] : 0;
    int ex = wbase + incl - s;
    #pragma unroll
    for (int j = 0; j < 4; ++j) {
        const int i = t * 4 + j;
        if (i < NBUCKET) { pos[i] = ex; ex += v[j]; }   // own indices only: no hazard
    }
    if (t == 0) pos[NBUCKET] = EPC;
    __syncthreads();

    // persist per-chunk prefix (coalesced)
    int* pg = pos_g + (size_t)c * NPOS;
    for (int i = t; i < NPOS; i += 1024) pg[i] = pos[i];
    __syncthreads();   // persist reads must finish before cursors mutate

    // pass 2: rank + scatter to LDS
    #pragma unroll 1
    for (int j = t; j < EPC; j += 1024) {
        const int row = erow[e0 + j];
        const int col = ecol[e0 + j];
        const float val = evals[e0 + j];
        const int r = atomicAdd(&pos[row >> 5], 1);
        uint2 ed;
        ed.x = (unsigned int)col | (((unsigned int)row & 31u) << 20);
        ed.y = __float_as_uint(val);
        sd[r] = ed;
    }
    __syncthreads();

    // write sorted chunk, fully coalesced
    uint2* sg = sedge + (size_t)c * EPC;
    for (int i = t; i < EPC; i += 1024) sg[i] = sd[i];
}

// ---------------- Kernel 3: transpose pos[256][3126] -> posT[3126][256] ----------------
// Gather block k then reads rows k, k+1 of posT as two coalesced 1 KB loads.
__global__ __launch_bounds__(256) void transpose_kernel(
    const int* __restrict__ pos_g, int* __restrict__ posT) {
    __shared__ int tile[64][65];
    const int k0 = blockIdx.x * 64;
    const int c0 = blockIdx.y * 64;
    const int t = threadIdx.x;
    #pragma unroll
    for (int m = 0; m < 16; ++m) {
        const int idx = m * 256 + t;
        const int i = idx >> 6, j = idx & 63;     // i: local c, j: local k (contiguous read)
        const int cc = c0 + i, kk = k0 + j;
        if (cc < NCHUNK && kk < NPOS)
            tile[j][i] = pos_g[(size_t)cc * NPOS + kk];
    }
    __syncthreads();
    #pragma unroll
    for (int m = 0; m < 16; ++m) {
        const int idx = m * 256 + t;
        const int j = idx >> 6, i = idx & 63;     // i: local c (contiguous write)
        const int kk = k0 + j, cc = c0 + i;
        if (kk < NPOS && cc < NCHUNK)
            posT[(size_t)kk * NCHUNK + cc] = tile[j][i];
    }
}

// ---------------- Kernel 4: gather = run-fetch + counting-sort by row + accumulation ---------
// Thread t = chunk t. Runs located via posT rows k/k+1 (coalesced); block scan of run
// lengths places runs in arrival order in tmp[] (LDS). Downstream identical to the
// proven gather: 32-way counting sort into sdata, then 4 edge-groups x 16 lanes x
// 4 cols/lane accumulation with shfl_xor cross-group reduce and float4 store.
// Bijective XCD swizzle (m204): adjacent buckets share sedge/posT lines -> same L2.
__global__ __launch_bounds__(256) void gather_kernel(
    const unsigned short* __restrict__ support, const uint2* __restrict__ sedge,
    const int* __restrict__ posT, const float* __restrict__ bias,
    float* __restrict__ out) {
    __shared__ uint2 tmp[CAP];      // 8 KB arrival-order edges
    __shared__ uint2 sdata[CAP];    // 8 KB row-sorted edges
    __shared__ int bcnt[BROWS];
    __shared__ int bptr[BROWS + 1];
    __shared__ int boff[BROWS];
    __shared__ int wsum[4];

    const int t = threadIdx.x;
    // nwg = 3125 = 8*390 + 5: xcd<5 owns 391 buckets, else 390 (bijective)
    const int orig = blockIdx.x;
    const int xcd = orig & 7, loc = orig >> 3;
    const int k = (xcd < 5 ? xcd * 391 : 5 * 391 + (xcd - 5) * 390) + loc;

    const int lane = t & 63, wid = t >> 6;

    // run descriptor for chunk t
    const int s = posT[(size_t)k * NCHUNK + t];
    const int e = posT[(size_t)(k + 1) * NCHUNK + t];
    const int L = e - s;

    // block scan of run lengths -> arrival offset
    int incl = L;
    #pragma unroll
    for (int d = 1; d < 64; d <<= 1) { int tv = __shfl_up(incl, d); if (lane >= d) incl += tv; }
    if (lane == 63) wsum[wid] = incl;
    if (t < BROWS) bcnt[t] = 0;
    __syncthreads();
    int wbase = 0;
    #pragma unroll
    for (int wj = 0; wj < 4; ++wj) wbase += (wj < wid) ? wsum[wj] : 0;
    const int ofs = wbase + incl - L;
    const int ntot = wsum[0] + wsum[1] + wsum[2] + wsum[3];
    const int n = min(ntot, CAP);

    // stash runs into tmp (arrival order); avg L = 2
    const uint2* myrun = sedge + (size_t)t * EPC + s;
    for (int j = 0; j < L; ++j) {
        const int p = ofs + j;
        if (p < CAP) tmp[p] = myrun[j];
    }
    __syncthreads();

    // counting sort by row-in-bucket
    uint2 my[4]; int mb[4];
    #pragma unroll
    for (int j = 0; j < 4; ++j) {
        const int i = t + j * 256;
        mb[j] = -1;
        if (i < n) {
            my[j] = tmp[i];
            mb[j] = (my[j].x >> 20) & 31;
            atomicAdd(&bcnt[mb[j]], 1);
        }
    }
    __syncthreads();

    if (t < 64) {
        const int v = (t < BROWS) ? bcnt[t] : 0;
        int incl2 = v;
        #pragma unroll
        for (int d = 1; d < 32; d <<= 1) { int tv = __shfl_up(incl2, d); if (t >= d) incl2 += tv; }
        if (t < BROWS) { bptr[t] = incl2 - v; boff[t] = incl2 - v; }
        if (t == BROWS - 1) bptr[BROWS] = incl2;
    }
    __syncthreads();

    #pragma unroll
    for (int j = 0; j < 4; ++j) {
        if (mb[j] >= 0) {
            const int p = atomicAdd(&boff[mb[j]], 1);
            sdata[p] = my[j];
        }
    }
    __syncthreads();

    const int eg = lane >> 4;          // edge-group 0..3
    const int c4 = lane & 15;          // col-quad: cols 4*c4 .. 4*c4+3
    const float4 bb = ((const float4*)bias)[c4];

    for (int r8 = 0; r8 < 8; ++r8) {
        const int r = wid * 8 + r8;
        const int s0 = bptr[r], s1 = bptr[r + 1];
        float a0 = 0.f, a1 = 0.f, a2 = 0.f, a3 = 0.f;
        int j = s0;
        for (; j + 8 <= s1; j += 8) {            // 2 quads in flight
            const uint2 e0 = sdata[j + eg];
            const uint2 e1 = sdata[j + 4 + eg];
            const uint2 g0 = *(const uint2*)(support + (size_t)(e0.x & 0xFFFFFu) * OUT_F + c4 * 4);
            const uint2 g1 = *(const uint2*)(support + (size_t)(e1.x & 0xFFFFFu) * OUT_F + c4 * 4);
            const float v0 = __uint_as_float(e0.y), v1 = __uint_as_float(e1.y);
            a0 += v0 * bflo(g0.x); a1 += v0 * bfhi(g0.x);
            a2 += v0 * bflo(g0.y); a3 += v0 * bfhi(g0.y);
            a0 += v1 * bflo(g1.x); a1 += v1 * bfhi(g1.x);
            a2 += v1 * bflo(g1.y); a3 += v1 * bfhi(g1.y);
        }
        for (; j < s1; j += 4) {                 // predicated quad tail
            const int jj = j + eg;
            const bool act = jj < s1;
            const uint2 ed = sdata[act ? jj : j];
            const float v = act ? __uint_as_float(ed.y) : 0.f;
            const uint2 gv = *(const uint2*)(support + (size_t)(ed.x & 0xFFFFFu) * OUT_F + c4 * 4);
            a0 += v * bflo(gv.x); a1 += v * bfhi(gv.x);
            a2 += v * bflo(gv.y); a3 += v * bfhi(gv.y);
        }
        a0 += __shfl_xor(a0, 16); a0 += __shfl_xor(a0, 32);
        a1 += __shfl_xor(a1, 16); a1 += __shfl_xor(a1, 32);
        a2 += __shfl_xor(a2, 16); a2 += __shfl_xor(a2, 32);
        a3 += __shfl_xor(a3, 16); a3 += __shfl_xor(a3, 32);
        if (eg == 0) {
            float4 o;
            o.x = a0 + bb.x; o.y = a1 + bb.y; o.z = a2 + bb.z; o.w = a3 + bb.w;
            *(float4*)(out + (size_t)(k * BROWS + r) * OUT_F + c4 * 4) = o;
        }
    }

    if (ntot > CAP) {   // overflow insurance (statistically never: CAP is 22 sigma out)
        __syncthreads();                          // out stores done; tmp dead
        for (int j = 0; j < L; ++j) {
            const int p = ofs + j;
            if (p >= CAP && p - CAP < CAP) tmp[p - CAP] = myrun[j];
        }
        __syncthreads();
        const int nov = min(ntot - CAP, CAP);
        for (int i = wid; i < nov; i += 4) {      // wave per edge, lane = column
            const uint2 ed = tmp[i];
            const float g = bf16_to_f32(support[(size_t)(ed.x & 0xFFFFFu) * OUT_F + lane]);
            atomicAdd(&out[(size_t)(k * BROWS + ((ed.x >> 20) & 31)) * OUT_F + lane],
                      g * __uint_as_float(ed.y));
        }
    }
}

// ---------------- Fallback (ws too small): bias-init + atomic scatter ----------------
__global__ __launch_bounds__(256) void init_out_kernel(const float* __restrict__ bias,
                                                       float* __restrict__ out) {
    const size_t i = (size_t)blockIdx.x * 256 + threadIdx.x;
    if (i < (size_t)N_NODES * OUT_F) out[i] = bias[i & 63];
}
__global__ __launch_bounds__(256) void scatter_atomic_kernel(
    const unsigned short* __restrict__ support, const int* __restrict__ erow,
    const int* __restrict__ ecol, const float* __restrict__ evals,
    float* __restrict__ out) {
    const int wid = (blockIdx.x * 256 + threadIdx.x) >> 6;
    const int nw = gridDim.x * 4;
    const int lane = threadIdx.x & 63;
    const int n_iters = N_EDGES / 8;
    for (int it0 = wid; it0 < n_iters; it0 += nw) {
        const int e0 = __builtin_amdgcn_readfirstlane(it0) * 8;
        int src[8], dst[8]; float val[8];
        #pragma unroll
        for (int u = 0; u < 8; ++u) { src[u] = ecol[e0 + u]; dst[u] = erow[e0 + u]; val[u] = evals[e0 + u]; }
        float g[8];
        #pragma unroll
        for (int u = 0; u < 8; ++u) g[u] = bf16_to_f32(support[(size_t)src[u] * OUT_F + lane]);
        #pragma unroll
        for (int u = 0; u < 8; ++u) atomicAdd(&out[(size_t)dst[u] * OUT_F + lane], g[u] * val[u]);
    }
}

extern "C" void kernel_launch(void* const* d_in, const int* in_sizes, int n_in,
                              void* d_out, int out_size, void* d_ws, size_t ws_size,
                              hipStream_t stream) {
    const float* x     = (const float*)d_in[0];
    const float* w     = (const float*)d_in[1];
    const float* bias  = (const float*)d_in[2];
    const int* erow    = (const int*)d_in[3];
    const int* ecol    = (const int*)d_in[4];
    const float* evals = (const float*)d_in[5];
    float* out = (float*)d_out;

    char* p = (char*)d_ws;
    unsigned short* support = (unsigned short*)p;  size_t o = (size_t)N_NODES * OUT_F * 2;   // 12.8 MB
    int* pos_g = (int*)(p + o);                    o += (size_t)NCHUNK * NPOS * 4;            // 3.2 MB
    int* posT  = (int*)(p + o);                    o += (size_t)NPOS * NCHUNK * 4;            // 3.2 MB
    uint2* sedge = (uint2*)(p + o);                o += (size_t)N_EDGES * 8;                  // 12.8 MB

    gemm_kernel<<<(N_NODES + 63) / 64, 256, 0, stream>>>(x, w, support);

    if (ws_size >= o) {
        sort_kernel<<<NCHUNK, 1024, 0, stream>>>(erow, ecol, evals, pos_g, sedge);
        transpose_kernel<<<dim3((NPOS + 63) / 64, NCHUNK / 64), 256, 0, stream>>>(pos_g, posT);
        gather_kernel<<<NBUCKET, 256, 0, stream>>>(support, sedge, posT, bias, out);
    } else {
        init_out_kernel<<<((N_NODES * OUT_F) + 255) / 256, 256, 0, stream>>>(bias, out);
        scatter_atomic_kernel<<<2048, 256, 0, stream>>>(support, erow, ecol, evals, out);
    }
}